// Round 1
// baseline (44107.361 us; speedup 1.0000x reference)
//
#include <hip/hip_runtime.h>
#include <math.h>

// DetectionLoss: masked pairwise IoU + exact Hungarian (Jonker-Volgenant
// shortest augmenting path) per image + scalar loss.
//
// Structure: one wave (64 lanes) per image, 8 blocks. All JV state in LDS;
// cost entries a[i0][j] = -IoU(i0-1, j-1) recomputed on the fly from
// LDS-resident boxes (cheaper than an L2 load, avoids workspace cost matrix).
// The algorithm is inherently serial (augmenting paths), so the design goal
// is minimum per-step latency: wave-wide shfl_xor argmin, 1-wave barriers.

constexpr int BIMG = 8;
constexpr int NBOX = 200;
constexpr int MCOL = NBOX + 1;   // 201 (JV uses a dummy column/row 0)
constexpr float SCORE_THR = 0.001f;

__device__ __forceinline__ bool class_allowed(int c) {
    return c == 1 || c == 2 || c == 3 || c == 5 || c == 7;
}

__global__ void __launch_bounds__(64)
det_loss_kernel(const float* __restrict__ boxes1,
                const float* __restrict__ boxes2,
                float* __restrict__ per_img) {
    const int b = blockIdx.x;
    const int lane = threadIdx.x;

    __shared__ float s1[NBOX][6];
    __shared__ float s2[NBOX][6];
    __shared__ float area1[NBOX], area2[NBOX];
    __shared__ int   key1[NBOX], key2[NBOX];     // class if valid else -1
    __shared__ float u[MCOL], v[MCOL], minv[MCOL];
    __shared__ int   way[MCOL], p[MCOL], usedf[MCOL];
    __shared__ int   cnt1, cnt2;

    const float* g1 = boxes1 + (size_t)b * NBOX * 6;
    const float* g2 = boxes2 + (size_t)b * NBOX * 6;
    for (int t = lane; t < NBOX * 6; t += 64) {
        (&s1[0][0])[t] = g1[t];
        (&s2[0][0])[t] = g2[t];
    }
    if (lane == 0) { cnt1 = 0; cnt2 = 0; }
    __syncthreads();

    for (int t = lane; t < NBOX; t += 64) {
        {
            int c = (int)s1[t][5];
            bool val = (s1[t][4] > SCORE_THR) && class_allowed(c);
            key1[t] = val ? c : -1;
            area1[t] = (s1[t][2] - s1[t][0]) * (s1[t][3] - s1[t][1]);
            if (val) atomicAdd(&cnt1, 1);
        }
        {
            int c = (int)s2[t][5];
            bool val = (s2[t][4] > SCORE_THR) && class_allowed(c);
            key2[t] = val ? c : -1;
            area2[t] = (s2[t][2] - s2[t][0]) * (s2[t][3] - s2[t][1]);
            if (val) atomicAdd(&cnt2, 1);
        }
    }
    for (int j = lane; j < MCOL; j += 64) { u[j] = 0.f; v[j] = 0.f; p[j] = 0; }
    __syncthreads();

    // IoU with class/validity mask; exact match to reference semantics:
    // mask = same_cls & valid1 & valid2  (key<0 encodes invalid).
    auto iou_fn = [&](int ii, int jj) -> float {
        int k = key1[ii];
        if (k < 0 || k != key2[jj]) return 0.f;
        float x1 = fmaxf(s1[ii][0], s2[jj][0]);
        float y1 = fmaxf(s1[ii][1], s2[jj][1]);
        float x2 = fminf(s1[ii][2], s2[jj][2]);
        float y2 = fminf(s1[ii][3], s2[jj][3]);
        float iw = fmaxf(x2 - x1, 0.f);
        float ih = fmaxf(y2 - y1, 0.f);
        float inter = iw * ih;
        float uni = area1[ii] + area2[jj] - inter;  // > 0 always (wh >= 10)
        return inter / uni;
    };

    // Jonker-Volgenant shortest augmenting path, square n=200.
    for (int i = 1; i <= NBOX; ++i) {
        if (lane == 0) p[0] = i;
        for (int j = lane; j < MCOL; j += 64) { minv[j] = INFINITY; usedf[j] = 0; }
        int j0 = 0;
        __syncthreads();

        while (true) {
            if (lane == 0) usedf[j0] = 1;
            __syncthreads();
            const int i0 = p[j0];          // uniform (broadcast LDS read)
            const float u0 = u[i0];

            // minv/way update over unused columns (4 columns per lane)
            for (int j = lane; j < MCOL; j += 64) {
                if (!usedf[j]) {
                    float aij = (j == 0) ? 0.f : -iou_fn(i0 - 1, j - 1);
                    float cur = aij - u0 - v[j];
                    if (cur < minv[j]) { minv[j] = cur; way[j] = j0; }
                }
            }
            __syncthreads();

            // argmin over unused columns; tie-break = smallest index (numpy argmin)
            float bv = INFINITY;
            int   bj = MCOL;
            for (int j = lane; j < MCOL; j += 64) {
                float m = usedf[j] ? INFINITY : minv[j];
                if (m < bv || (m == bv && j < bj)) { bv = m; bj = j; }
            }
            #pragma unroll
            for (int off = 32; off; off >>= 1) {
                float ov = __shfl_xor(bv, off);
                int   oj = __shfl_xor(bj, off);
                if (ov < bv || (ov == bv && oj < bj)) { bv = ov; bj = oj; }
            }
            j0 = bj;                       // uniform after full-wave reduce
            const float delta = bv;

            // dual update: u[p[used]] += delta; v[used] -= delta; minv[~used] -= delta
            for (int j = lane; j < MCOL; j += 64) {
                if (usedf[j]) { u[p[j]] += delta; v[j] -= delta; }
                else          { minv[j] -= delta; }
            }
            __syncthreads();
            if (p[j0] == 0) break;
        }

        // augment along the alternating path (serial, lane 0)
        if (lane == 0) {
            int jj = j0;
            while (jj != 0) {
                int j1 = way[jj];
                p[jj] = p[j1];
                jj = j1;
            }
        }
        __syncthreads();
    }

    // matched sum: sum_j>=1 IoU(p[j]-1, j-1)  (perfect matching on square matrix)
    float s = 0.f;
    for (int j = lane; j < MCOL; j += 64) {
        if (j > 0) {
            int pi = p[j];
            s += iou_fn(pi - 1, j - 1);
        }
    }
    #pragma unroll
    for (int off = 32; off; off >>= 1) s += __shfl_xor(s, off);

    if (lane == 0) {
        float na = (float)cnt1;
        float nb = (float)cnt2;
        float denom = fmaxf(fmaxf(na, nb), 1.f);
        float per = 1.f - s / denom;
        bool both_zero = (na == 0.f) && (nb == 0.f);
        bool one_zero  = ((na == 0.f) != (nb == 0.f));
        per = both_zero ? 0.f : (one_zero ? 1.f : per);
        per_img[b] = per;
    }
}

__global__ void finalize_kernel(const float* __restrict__ per_img,
                                float* __restrict__ out) {
    if (threadIdx.x == 0 && blockIdx.x == 0) {
        float s = 0.f;
        #pragma unroll
        for (int b = 0; b < BIMG; ++b) s += per_img[b];
        out[0] = s / (float)BIMG;
    }
}

extern "C" void kernel_launch(void* const* d_in, const int* in_sizes, int n_in,
                              void* d_out, int out_size, void* d_ws, size_t ws_size,
                              hipStream_t stream) {
    const float* b1 = (const float*)d_in[0];
    const float* b2 = (const float*)d_in[1];
    float* per_img = (float*)d_ws;   // 8 floats of scratch
    float* out = (float*)d_out;

    det_loss_kernel<<<BIMG, 64, 0, stream>>>(b1, b2, per_img);
    finalize_kernel<<<1, 64, 0, stream>>>(per_img, out);
}

// Round 2
// 104.854 us; speedup vs baseline: 420.6543x; 420.6543x over previous
//
#include <hip/hip_runtime.h>
#include <math.h>

// DetectionLoss: masked pairwise IoU + exact Hungarian + scalar loss.
//
// Key structure (r2): the cost matrix is nonzero ONLY for same-class valid
// pairs, so the 200x200 assignment decomposes exactly into 5 independent
// per-class subproblems (~20x20 each). One block (1 wave) per (image,class):
// 8*5 = 40 blocks. Within a block, JV shortest-augmenting-path with:
//   - prefer-UNMATCHED tie-break in the Dijkstra argmin (any minimal node is
//     a valid Dijkstra choice; optimal sum unchanged; kills the O(n) walks
//     through tied matched columns that made r1 take 44 ms)
//   - n<=64 fast path: one column per lane, ALL state in registers
//     (u,v,minv,way,p,used + box coords), inner loop is pure shfl/VALU —
//     no LDS, no barriers. LDS fallback for n>64 (practically unreachable).

constexpr int BIMG = 8;
constexpr int NBOX = 200;
constexpr int NCLS = 5;
constexpr float SCORE_THR = 0.001f;

__global__ void __launch_bounds__(64)
det_match_kernel(const float* __restrict__ boxes1,
                 const float* __restrict__ boxes2,
                 float* __restrict__ sum_iou,
                 int* __restrict__ na, int* __restrict__ nb)
{
    const int lane = threadIdx.x;
    const int b    = blockIdx.x / NCLS;
    const int ci   = blockIdx.x % NCLS;
    const int cls  = (ci == 0) ? 1 : (ci == 1) ? 2 : (ci == 2) ? 3 : (ci == 3) ? 5 : 7;

    __shared__ float r1x1[NBOX], r1y1[NBOX], r1x2[NBOX], r1y2[NBOX], r1a[NBOX];
    __shared__ float r2x1[NBOX], r2y1[NBOX], r2x2[NBOX], r2y2[NBOX], r2a[NBOX];
    // fallback-only JV state (n > 64)
    __shared__ float uarr[NBOX + 1], varr[NBOX + 1], minvarr[NBOX + 1];
    __shared__ int   wayarr[NBOX + 1], parr[NBOX + 1], usedarr[NBOX + 1];

    const float* g1 = boxes1 + (size_t)b * NBOX * 6;
    const float* g2 = boxes2 + (size_t)b * NBOX * 6;
    const unsigned long long ltmask = (1ull << lane) - 1ull;

    // ---- filter to this class, ballot-compact into LDS (deterministic order)
    int m1 = 0, m2 = 0;
    for (int c0 = 0; c0 < NBOX; c0 += 64) {
        int t = c0 + lane;
        bool in = (t < NBOX);
        float x1 = 0, y1 = 0, x2 = 0, y2 = 0, sc = 0, cf = 0;
        if (in) {
            const float* p = g1 + (size_t)t * 6;
            x1 = p[0]; y1 = p[1]; x2 = p[2]; y2 = p[3]; sc = p[4]; cf = p[5];
        }
        bool pr = in && (sc > SCORE_THR) && ((int)cf == cls);
        unsigned long long mk = __ballot(pr);
        int pos = m1 + __popcll(mk & ltmask);
        if (pr) { r1x1[pos] = x1; r1y1[pos] = y1; r1x2[pos] = x2; r1y2[pos] = y2;
                  r1a[pos] = (x2 - x1) * (y2 - y1); }
        m1 += __popcll(mk);

        if (in) {
            const float* p = g2 + (size_t)t * 6;
            x1 = p[0]; y1 = p[1]; x2 = p[2]; y2 = p[3]; sc = p[4]; cf = p[5];
        }
        pr = in && (sc > SCORE_THR) && ((int)cf == cls);
        mk = __ballot(pr);
        pos = m2 + __popcll(mk & ltmask);
        if (pr) { r2x1[pos] = x1; r2y1[pos] = y1; r2x2[pos] = x2; r2y2[pos] = y2;
                  r2a[pos] = (x2 - x1) * (y2 - y1); }
        m2 += __popcll(mk);
    }
    __syncthreads();

    if (lane == 0) { atomicAdd(&na[b], m1); atomicAdd(&nb[b], m2); }
    if (m1 == 0 || m2 == 0) return;   // all-zero subproblem contributes 0 IoU
    const int n = (m1 > m2) ? m1 : m2;  // pad to square with zero-cost entries

    if (n <= 64) {
        // ======================= register fast path =======================
        const int  col       = lane + 1;
        const bool colActive = (col <= n);
        const bool realCol   = (col <= m2);
        float cbx1 = 0, cby1 = 0, cbx2 = 0, cby2 = 0, cba = 0;
        if (realCol) { cbx1 = r2x1[lane]; cby1 = r2y1[lane]; cbx2 = r2x2[lane];
                       cby2 = r2y2[lane]; cba = r2a[lane]; }
        float rbx1 = 0, rby1 = 0, rbx2 = 0, rby2 = 0, rba = 0;
        if (lane < m1) { rbx1 = r1x1[lane]; rby1 = r1y1[lane]; rbx2 = r1x2[lane];
                         rby2 = r1y2[lane]; rba = r1a[lane]; }

        float ur = 0.f;   // dual u of row (lane+1)
        float vj = 0.f;   // dual v of this column
        int   pj = 0;     // row matched to this column (0 = unmatched)

        for (int i = 1; i <= n; ++i) {
            float minvj = INFINITY;
            int   wayj  = 0;
            bool  usedj = !colActive;
            bool  inTree = (lane == i - 1);   // rows of the alternating tree
            int   j0 = 0;

            for (int it = 0; it <= n + 1; ++it) {
                int i0;
                if (j0 == 0) { i0 = i; }
                else {
                    if (lane == j0 - 1) usedj = true;
                    i0 = __shfl(pj, j0 - 1);
                }
                if (lane == i0 - 1) inTree = true;
                const float u0 = __shfl(ur, i0 - 1);

                const bool rowReal = (i0 <= m1);          // uniform
                float rx1 = 0, ry1 = 0, rx2 = 0, ry2 = 0, ra = 0;
                if (rowReal) {                            // uniform branch: shfl safe
                    rx1 = __shfl(rbx1, i0 - 1); ry1 = __shfl(rby1, i0 - 1);
                    rx2 = __shfl(rbx2, i0 - 1); ry2 = __shfl(rby2, i0 - 1);
                    ra  = __shfl(rba,  i0 - 1);
                }
                float cost = 0.f;
                if (realCol && rowReal) {
                    float ix1 = fmaxf(rx1, cbx1), iy1 = fmaxf(ry1, cby1);
                    float ix2 = fminf(rx2, cbx2), iy2 = fminf(ry2, cby2);
                    float iw = fmaxf(ix2 - ix1, 0.f), ih = fmaxf(iy2 - iy1, 0.f);
                    float inter = iw * ih;
                    cost = -(inter / (ra + cba - inter));
                }
                float cur = cost - u0 - vj;
                if (!usedj && cur < minvj) { minvj = cur; wayj = j0; }

                // argmin over unused cols; tie-break: prefer UNMATCHED, then low idx
                float bv = usedj ? INFINITY : minvj;
                int   bu = (pj == 0) ? 1 : 0;
                int   bj = col;
                #pragma unroll
                for (int off = 32; off; off >>= 1) {
                    float ov = __shfl_xor(bv, off);
                    int   ou = __shfl_xor(bu, off);
                    int   oj = __shfl_xor(bj, off);
                    if (ov < bv || (ov == bv && (ou > bu || (ou == bu && oj < bj))))
                        { bv = ov; bu = ou; bj = oj; }
                }
                j0 = bj;
                const float delta = bv;

                if (inTree) ur += delta;                  // u[p[used]] += delta
                if (colActive) {
                    if (usedj) vj -= delta;               // v[used]    -= delta
                    else       minvj -= delta;            // minv[~used]-= delta
                }
                const int pj0 = __shfl(pj, j0 - 1);
                if (pj0 == 0) break;
            }

            // augment: p[j0] = p[way[j0]] back along the path
            int jj = j0;
            for (int it = 0; it <= n + 1 && jj != 0; ++it) {
                int j1 = __shfl(wayj, jj - 1);
                int src = (j1 == 0) ? 0 : (j1 - 1);
                int pv  = __shfl(pj, src);
                if (j1 == 0) pv = i;
                if (lane == jj - 1) pj = pv;
                jj = j1;
            }
        }

        // matched IoU sum for this class
        float contrib = 0.f;
        {
            const bool has = realCol && (pj >= 1) && (pj <= m1);
            int src = has ? (pj - 1) : 0;
            float rx1 = __shfl(rbx1, src), ry1 = __shfl(rby1, src);
            float rx2 = __shfl(rbx2, src), ry2 = __shfl(rby2, src);
            float ra  = __shfl(rba,  src);
            if (has) {
                float ix1 = fmaxf(rx1, cbx1), iy1 = fmaxf(ry1, cby1);
                float ix2 = fminf(rx2, cbx2), iy2 = fminf(ry2, cby2);
                float iw = fmaxf(ix2 - ix1, 0.f), ih = fmaxf(iy2 - iy1, 0.f);
                float inter = iw * ih;
                contrib = inter / (ra + cba - inter);
            }
        }
        #pragma unroll
        for (int off = 32; off; off >>= 1) contrib += __shfl_xor(contrib, off);
        if (lane == 0) atomicAdd(&sum_iou[b], contrib);
    } else {
        // ======================= LDS fallback (n > 64) ====================
        for (int j = lane; j <= n; j += 64) { varr[j] = 0.f; parr[j] = 0; uarr[j] = 0.f; }
        __syncthreads();

        int j0 = 0;
        for (int i = 1; i <= n; ++i) {
            if (lane == 0) parr[0] = i;
            for (int j = lane; j <= n; j += 64) { minvarr[j] = INFINITY; usedarr[j] = 0; }
            j0 = 0;
            __syncthreads();

            for (int it = 0; it <= n + 1; ++it) {
                if (lane == 0) usedarr[j0] = 1;
                __syncthreads();
                const int i0 = parr[j0];
                const float u0 = uarr[i0];
                const bool rowReal = (i0 <= m1);
                float rx1 = 0, ry1 = 0, rx2 = 0, ry2 = 0, ra = 0;
                if (rowReal) { rx1 = r1x1[i0-1]; ry1 = r1y1[i0-1]; rx2 = r1x2[i0-1];
                               ry2 = r1y2[i0-1]; ra = r1a[i0-1]; }
                for (int j = lane; j <= n; j += 64) {
                    if (j >= 1 && !usedarr[j]) {
                        float cost = 0.f;
                        if (rowReal && j <= m2) {
                            float ix1 = fmaxf(rx1, r2x1[j-1]), iy1 = fmaxf(ry1, r2y1[j-1]);
                            float ix2 = fminf(rx2, r2x2[j-1]), iy2 = fminf(ry2, r2y2[j-1]);
                            float iw = fmaxf(ix2 - ix1, 0.f), ih = fmaxf(iy2 - iy1, 0.f);
                            float inter = iw * ih;
                            cost = -(inter / (ra + r2a[j-1] - inter));
                        }
                        float cur = cost - u0 - varr[j];
                        if (cur < minvarr[j]) { minvarr[j] = cur; wayarr[j] = j0; }
                    }
                }
                __syncthreads();

                float bv = INFINITY; int bu = 0, bj = n + 1;
                for (int j = lane; j <= n; j += 64) {
                    float m = usedarr[j] ? INFINITY : minvarr[j];
                    int   un = (parr[j] == 0) ? 1 : 0;
                    if (m < bv || (m == bv && (un > bu || (un == bu && j < bj))))
                        { bv = m; bu = un; bj = j; }
                }
                #pragma unroll
                for (int off = 32; off; off >>= 1) {
                    float ov = __shfl_xor(bv, off);
                    int   ou = __shfl_xor(bu, off);
                    int   oj = __shfl_xor(bj, off);
                    if (ov < bv || (ov == bv && (ou > bu || (ou == bu && oj < bj))))
                        { bv = ov; bu = ou; bj = oj; }
                }
                j0 = bj;
                const float delta = bv;
                for (int j = lane; j <= n; j += 64) {
                    if (usedarr[j]) { uarr[parr[j]] += delta; varr[j] -= delta; }
                    else            { minvarr[j] -= delta; }
                }
                __syncthreads();
                if (parr[j0] == 0) break;
            }

            if (lane == 0) {
                int jj = j0, guard = 0;
                while (jj != 0 && guard++ <= n + 1) {
                    int j1 = wayarr[jj];
                    parr[jj] = parr[j1];
                    jj = j1;
                }
            }
            __syncthreads();
        }

        float contrib = 0.f;
        for (int j = lane; j <= n; j += 64) {
            if (j >= 1 && j <= m2) {
                int pi = parr[j];
                if (pi >= 1 && pi <= m1) {
                    float ix1 = fmaxf(r1x1[pi-1], r2x1[j-1]), iy1 = fmaxf(r1y1[pi-1], r2y1[j-1]);
                    float ix2 = fminf(r1x2[pi-1], r2x2[j-1]), iy2 = fminf(r1y2[pi-1], r2y2[j-1]);
                    float iw = fmaxf(ix2 - ix1, 0.f), ih = fmaxf(iy2 - iy1, 0.f);
                    float inter = iw * ih;
                    contrib += inter / (r1a[pi-1] + r2a[j-1] - inter);
                }
            }
        }
        #pragma unroll
        for (int off = 32; off; off >>= 1) contrib += __shfl_xor(contrib, off);
        if (lane == 0) atomicAdd(&sum_iou[b], contrib);
    }
}

__global__ void det_finalize_kernel(const float* __restrict__ sum_iou,
                                    const int* __restrict__ na,
                                    const int* __restrict__ nb,
                                    float* __restrict__ out)
{
    if (threadIdx.x == 0 && blockIdx.x == 0) {
        float acc = 0.f;
        #pragma unroll
        for (int b = 0; b < BIMG; ++b) {
            int a = na[b], c = nb[b];
            float denom = fmaxf(fmaxf((float)a, (float)c), 1.f);
            float per = 1.f - sum_iou[b] / denom;
            bool bz = (a == 0) && (c == 0);
            bool oz = ((a == 0) != (c == 0));
            per = bz ? 0.f : (oz ? 1.f : per);
            acc += per;
        }
        out[0] = acc / (float)BIMG;
    }
}

extern "C" void kernel_launch(void* const* d_in, const int* in_sizes, int n_in,
                              void* d_out, int out_size, void* d_ws, size_t ws_size,
                              hipStream_t stream) {
    const float* b1 = (const float*)d_in[0];
    const float* b2 = (const float*)d_in[1];
    float* sum_iou = (float*)d_ws;            // [8] f32
    int*   na      = (int*)(sum_iou + BIMG);  // [8] i32
    int*   nb      = na + BIMG;               // [8] i32
    hipMemsetAsync(d_ws, 0, 3 * BIMG * sizeof(float), stream);
    det_match_kernel<<<BIMG * NCLS, 64, 0, stream>>>(b1, b2, sum_iou, na, nb);
    det_finalize_kernel<<<1, 64, 0, stream>>>(sum_iou, na, nb, (float*)d_out);
}

// Round 3
// 77.244 us; speedup vs baseline: 571.0125x; 1.3574x over previous
//
#include <hip/hip_runtime.h>
#include <math.h>

// DetectionLoss: masked pairwise IoU + exact Hungarian + scalar loss.
//
// r3 structure: per-(image,class) subproblem (cost nonzero only for
// same-class valid pairs -> exact decomposition). One wave per block.
//   - NZ filtering: rows/cols with no positive-IoU entry are dropped
//     (contribute 0; #cols >= #rows keeps the optimum intact). Problem
//     shrinks from ~25x25 to ~12x12.
//   - JV shortest-augmenting-path with prefer-unmatched tie-break.
//   - All JV state in REGISTERS, one column per lane. Each column lane
//     carries its matched row's box+area+dual, so tree expansion is ONE
//     parallel shfl layer from lane j0-1.
//   - 64-lane argmin via 6-step DPP butterfly (quad_perm/mirror/bcast)
//     on a packed (monotonic-float, payload) pair: zero LDS-pipe ops.
//   - No atomics/memset: per-block workspace slots + tiny finalize kernel.

constexpr int BIMG = 8;
constexpr int NBOX = 200;
constexpr int NCLS = 5;
constexpr float SCORE_THR = 0.001f;

__device__ __forceinline__ unsigned fkey(float f) {
    unsigned u = __float_as_uint(f);
    return (u & 0x80000000u) ? ~u : (u | 0x80000000u);
}
__device__ __forceinline__ float fkey_inv(unsigned k) {
    unsigned u = (k & 0x80000000u) ? (k ^ 0x80000000u) : ~k;
    return __uint_as_float(u);
}

// one lexicographic-min step on (ik, ip); CTRL must be a literal.
// update_dpp(old=self, ...) + bound_ctrl=false -> invalid lanes keep old
// (self-compare no-op), required for the row_bcast steps.
#define ARGMIN_DPP_STEP(CTRL)                                                \
    {                                                                        \
        unsigned ok = (unsigned)__builtin_amdgcn_update_dpp(                 \
            (int)ik, (int)ik, (CTRL), 0xF, 0xF, false);                      \
        unsigned op = (unsigned)__builtin_amdgcn_update_dpp(                 \
            (int)ip, (int)ip, (CTRL), 0xF, 0xF, false);                      \
        bool lt = (ok < ik) || ((ok == ik) && (op < ip));                    \
        ik = lt ? ok : ik;                                                   \
        ip = lt ? op : ip;                                                   \
    }

__global__ void __launch_bounds__(64)
det_match_kernel(const float* __restrict__ boxes1,
                 const float* __restrict__ boxes2,
                 float* __restrict__ sum_part,
                 int* __restrict__ m1_part, int* __restrict__ m2_part)
{
    const int lane = threadIdx.x;
    const int blk  = blockIdx.x;
    const int b    = blk / NCLS;
    const int ci   = blk % NCLS;
    const int cls  = (ci == 0) ? 1 : (ci == 1) ? 2 : (ci == 2) ? 3 : (ci == 3) ? 5 : 7;

    __shared__ float r1x1[NBOX], r1y1[NBOX], r1x2[NBOX], r1y2[NBOX], r1a[NBOX];
    __shared__ float r2x1[NBOX], r2y1[NBOX], r2x2[NBOX], r2y2[NBOX], r2a[NBOX];
    // fallback-only JV state (n > 64; practically unreachable)
    __shared__ float uarr[NBOX + 1], varr[NBOX + 1], minvarr[NBOX + 1];
    __shared__ int   wayarr[NBOX + 1], parr[NBOX + 1], usedarr[NBOX + 1];

    const float* g1 = boxes1 + (size_t)b * NBOX * 6;
    const float* g2 = boxes2 + (size_t)b * NBOX * 6;
    const unsigned long long ltmask = (1ull << lane) - 1ull;

    // ---- phase 1: filter to this class, ballot-compact into LDS
    int m1 = 0, m2 = 0;
    for (int c0 = 0; c0 < NBOX; c0 += 64) {
        int t = c0 + lane;
        bool in = (t < NBOX);
        float x1 = 0, y1 = 0, x2 = 0, y2 = 0, sc = 0, cf = 0;
        if (in) {
            const float* p = g1 + (size_t)t * 6;
            x1 = p[0]; y1 = p[1]; x2 = p[2]; y2 = p[3]; sc = p[4]; cf = p[5];
        }
        bool pr = in && (sc > SCORE_THR) && ((int)cf == cls);
        unsigned long long mk = __ballot(pr);
        int pos = m1 + __popcll(mk & ltmask);
        if (pr) { r1x1[pos] = x1; r1y1[pos] = y1; r1x2[pos] = x2; r1y2[pos] = y2;
                  r1a[pos] = (x2 - x1) * (y2 - y1); }
        m1 += __popcll(mk);

        if (in) {
            const float* p = g2 + (size_t)t * 6;
            x1 = p[0]; y1 = p[1]; x2 = p[2]; y2 = p[3]; sc = p[4]; cf = p[5];
        }
        pr = in && (sc > SCORE_THR) && ((int)cf == cls);
        mk = __ballot(pr);
        pos = m2 + __popcll(mk & ltmask);
        if (pr) { r2x1[pos] = x1; r2y1[pos] = y1; r2x2[pos] = x2; r2y2[pos] = y2;
                  r2a[pos] = (x2 - x1) * (y2 - y1); }
        m2 += __popcll(mk);
    }
    __syncthreads();

    if (lane == 0) { m1_part[blk] = m1; m2_part[blk] = m2; }
    if (m1 == 0 || m2 == 0) { if (lane == 0) sum_part[blk] = 0.f; return; }
    const int n = (m1 > m2) ? m1 : m2;

    if (n <= 64) {
        // ===================== register fast path ========================
        // orientation: rows = smaller side
        const bool swapped = (m1 > m2);
        float* rrx1 = swapped ? r2x1 : r1x1; float* rry1 = swapped ? r2y1 : r1y1;
        float* rrx2 = swapped ? r2x2 : r1x2; float* rry2 = swapped ? r2y2 : r1y2;
        float* rra  = swapped ? r2a  : r1a;
        float* ccx1 = swapped ? r1x1 : r2x1; float* ccy1 = swapped ? r1y1 : r2y1;
        float* ccx2 = swapped ? r1x2 : r2x2; float* ccy2 = swapped ? r1y2 : r2y2;
        float* cca  = swapped ? r1a  : r2a;
        int mr = swapped ? m2 : m1;
        int mc = swapped ? m1 : m2;

        float rbx1 = 0, rby1 = 0, rbx2 = 0, rby2 = 0, rba = 0;
        if (lane < mr) { rbx1 = rrx1[lane]; rby1 = rry1[lane]; rbx2 = rrx2[lane];
                         rby2 = rry2[lane]; rba = rra[lane]; }
        float cbx1 = 0, cby1 = 0, cbx2 = 0, cby2 = 0, cba = 0;
        if (lane < mc) { cbx1 = ccx1[lane]; cby1 = ccy1[lane]; cbx2 = ccx2[lane];
                         cby2 = ccy2[lane]; cba = cca[lane]; }

        // ---- NZ scan: which rows/cols have any positive-IoU entry
        unsigned long long rowmask = 0ull;
        bool colnz = false;
        for (int i = 0; i < mr; ++i) {
            float ax1 = rrx1[i], ay1 = rry1[i], ax2 = rrx2[i], ay2 = rry2[i];
            float iw = fminf(ax2, cbx2) - fmaxf(ax1, cbx1);
            float ih = fminf(ay2, cby2) - fmaxf(ay1, cby1);
            bool nz = (lane < mc) && (iw > 0.f) && (ih > 0.f);
            unsigned long long bal = __ballot(nz);
            if (bal) rowmask |= (1ull << i);
            colnz |= nz;
        }
        int mrP = __popcll(rowmask);
        if (mrP == 0) { if (lane == 0) sum_part[blk] = 0.f; return; }
        unsigned long long colmask = __ballot(colnz);
        int mcP = __popcll(colmask);

        // ---- compact kept rows/cols (LDS round-trip), reload regs
        __syncthreads();
        if (lane < mr && ((rowmask >> lane) & 1ull)) {
            int pos = __popcll(rowmask & ltmask);
            rrx1[pos] = rbx1; rry1[pos] = rby1; rrx2[pos] = rbx2; rry2[pos] = rby2;
            rra[pos] = rba;
        }
        if (lane < mc && ((colmask >> lane) & 1ull)) {
            int pos = __popcll(colmask & ltmask);
            ccx1[pos] = cbx1; ccy1[pos] = cby1; ccx2[pos] = cbx2; ccy2[pos] = cby2;
            cca[pos] = cba;
        }
        __syncthreads();
        rbx1 = rby1 = rbx2 = rby2 = rba = 0.f;
        if (lane < mrP) { rbx1 = rrx1[lane]; rby1 = rry1[lane]; rbx2 = rrx2[lane];
                          rby2 = rry2[lane]; rba = rra[lane]; }
        cbx1 = cby1 = cbx2 = cby2 = cba = 0.f;
        if (lane < mcP) { cbx1 = ccx1[lane]; cby1 = ccy1[lane]; cbx2 = ccx2[lane];
                          cby2 = ccy2[lane]; cba = cca[lane]; }
        if (mrP > mcP) {   // re-orient so rows <= cols
            float t;
            t = rbx1; rbx1 = cbx1; cbx1 = t;  t = rby1; rby1 = cby1; cby1 = t;
            t = rbx2; rbx2 = cbx2; cbx2 = t;  t = rby2; rby2 = cby2; cby2 = t;
            t = rba;  rba  = cba;  cba  = t;
            int ti = mrP; mrP = mcP; mcP = ti;
        }

        // ---- JV on mrP x mcP, all state per-lane (lane = column lane+1)
        float vj = 0.f;          // dual v of my column
        float urow = 0.f;        // dual u of my matched row
        float cmx1 = 0, cmy1 = 0, cmx2 = 0, cmy2 = 0, cma = 0;  // matched row box
        int   pmrow = 0;         // matched row id (0 = free)

        for (int i = 1; i <= mrP; ++i) {
            float minvj = INFINITY;
            int   wayj = 0;
            bool  usedj = (lane >= mcP);
            float u_free = 0.f;
            int   j0cur = 0;
            int   j0n = 0;
            // tree root: row i (one broadcast layer)
            float rx1 = __shfl(rbx1, i - 1), ry1 = __shfl(rby1, i - 1);
            float rx2 = __shfl(rbx2, i - 1), ry2 = __shfl(rby2, i - 1);
            float ra  = __shfl(rba,  i - 1);
            float u0 = 0.f;

            for (int guard = 0; guard <= 66; ++guard) {
                // cost of (tree row, my col); update minv
                float iou = 0.f;
                if (lane < mcP) {
                    float iw = fmaxf(fminf(rx2, cbx2) - fmaxf(rx1, cbx1), 0.f);
                    float ih = fmaxf(fminf(ry2, cby2) - fmaxf(ry1, cby1), 0.f);
                    float inter = iw * ih;
                    iou = inter / (ra + cba - inter);
                }
                float cur = -iou - u0 - vj;
                if (!usedj && cur < minvj) { minvj = cur; wayj = j0cur; }

                // 64-lane lexicographic argmin, all in VALU (DPP) + readlane
                unsigned ik = usedj ? 0xFFFFFFFFu : fkey(minvj);
                unsigned ip = usedj ? 0xFFFFFFFFu
                                    : ((pmrow ? 0x100u : 0u) | (unsigned)(lane + 1));
                ARGMIN_DPP_STEP(0xB1)   // quad_perm [1,0,3,2] : xor1
                ARGMIN_DPP_STEP(0x4E)   // quad_perm [2,3,0,1] : xor2
                ARGMIN_DPP_STEP(0x141)  // row_half_mirror     : xor7 in 8
                ARGMIN_DPP_STEP(0x140)  // row_mirror          : xor15 in 16
                ARGMIN_DPP_STEP(0x142)  // row_bcast15
                ARGMIN_DPP_STEP(0x143)  // row_bcast31 -> lane 63 = global min
                unsigned sk = (unsigned)__builtin_amdgcn_readlane((int)ik, 63);
                unsigned sp = (unsigned)__builtin_amdgcn_readlane((int)ip, 63);
                float delta = fkey_inv(sk);
                j0n = (int)(sp & 0xFFu);
                bool j0matched = (sp & 0x100u) != 0u;
                if (j0n == 0xFF) break;   // defensive: no selectable column

                // dual updates (all local)
                u_free += delta;
                if (usedj) { vj -= delta; if (pmrow) urow += delta; }
                else       { minvj -= delta; }

                if (!j0matched) break;    // p[j0] == 0 -> augmenting path found

                // expand column j0n: ONE parallel broadcast layer
                if (lane == j0n - 1) usedj = true;
                u0  = __shfl(urow, j0n - 1);
                rx1 = __shfl(cmx1, j0n - 1); ry1 = __shfl(cmy1, j0n - 1);
                rx2 = __shfl(cmx2, j0n - 1); ry2 = __shfl(cmy2, j0n - 1);
                ra  = __shfl(cma,  j0n - 1);
                j0cur = j0n;
            }

            // ---- augment along way[] back to the root
            int jj = j0n;
            float nx1 = __shfl(rbx1, i - 1), ny1 = __shfl(rby1, i - 1);
            float nx2 = __shfl(rbx2, i - 1), ny2 = __shfl(rby2, i - 1);
            float nar = __shfl(rba,  i - 1);
            for (int hop = 0; hop < 66 && jj != 0; ++hop) {
                int j1 = __shfl(wayj, jj - 1);
                if (j1 == 0) {
                    if (lane == jj - 1) {
                        pmrow = i; urow = u_free;
                        cmx1 = nx1; cmy1 = ny1; cmx2 = nx2; cmy2 = ny2; cma = nar;
                    }
                    jj = 0;
                } else {
                    int   ppj = __shfl(pmrow, j1 - 1);
                    float pur = __shfl(urow,  j1 - 1);
                    float px1 = __shfl(cmx1, j1 - 1), py1 = __shfl(cmy1, j1 - 1);
                    float px2 = __shfl(cmx2, j1 - 1), py2 = __shfl(cmy2, j1 - 1);
                    float pa  = __shfl(cma,  j1 - 1);
                    if (lane == jj - 1) {
                        pmrow = ppj; urow = pur;
                        cmx1 = px1; cmy1 = py1; cmx2 = px2; cmy2 = py2; cma = pa;
                    }
                    jj = j1;
                }
            }
        }

        // ---- matched IoU sum (each lane has its matched row's box locally)
        float contrib = 0.f;
        if (lane < mcP && pmrow != 0) {
            float iw = fmaxf(fminf(cmx2, cbx2) - fmaxf(cmx1, cbx1), 0.f);
            float ih = fmaxf(fminf(cmy2, cby2) - fmaxf(cmy1, cby1), 0.f);
            float inter = iw * ih;
            contrib = inter / (cma + cba - inter);
        }
        #pragma unroll
        for (int off = 32; off; off >>= 1) contrib += __shfl_xor(contrib, off);
        if (lane == 0) sum_part[blk] = contrib;
    } else {
        // ===================== LDS fallback (n > 64) =====================
        for (int j = lane; j <= n; j += 64) { varr[j] = 0.f; parr[j] = 0; uarr[j] = 0.f; }
        __syncthreads();

        int j0 = 0;
        for (int i = 1; i <= n; ++i) {
            if (lane == 0) parr[0] = i;
            for (int j = lane; j <= n; j += 64) { minvarr[j] = INFINITY; usedarr[j] = 0; }
            j0 = 0;
            __syncthreads();

            for (int it = 0; it <= n + 1; ++it) {
                if (lane == 0) usedarr[j0] = 1;
                __syncthreads();
                const int i0 = parr[j0];
                const float u0 = uarr[i0];
                const bool rowReal = (i0 <= m1);
                float rx1 = 0, ry1 = 0, rx2 = 0, ry2 = 0, ra = 0;
                if (rowReal) { rx1 = r1x1[i0-1]; ry1 = r1y1[i0-1]; rx2 = r1x2[i0-1];
                               ry2 = r1y2[i0-1]; ra = r1a[i0-1]; }
                for (int j = lane; j <= n; j += 64) {
                    if (j >= 1 && !usedarr[j]) {
                        float cost = 0.f;
                        if (rowReal && j <= m2) {
                            float ix1 = fmaxf(rx1, r2x1[j-1]), iy1 = fmaxf(ry1, r2y1[j-1]);
                            float ix2 = fminf(rx2, r2x2[j-1]), iy2 = fminf(ry2, r2y2[j-1]);
                            float iw = fmaxf(ix2 - ix1, 0.f), ih = fmaxf(iy2 - iy1, 0.f);
                            float inter = iw * ih;
                            cost = -(inter / (ra + r2a[j-1] - inter));
                        }
                        float cur = cost - u0 - varr[j];
                        if (cur < minvarr[j]) { minvarr[j] = cur; wayarr[j] = j0; }
                    }
                }
                __syncthreads();

                float bv = INFINITY; int bu = 0, bj = n + 1;
                for (int j = lane; j <= n; j += 64) {
                    float m = usedarr[j] ? INFINITY : minvarr[j];
                    int   un = (parr[j] == 0) ? 1 : 0;
                    if (m < bv || (m == bv && (un > bu || (un == bu && j < bj))))
                        { bv = m; bu = un; bj = j; }
                }
                #pragma unroll
                for (int off = 32; off; off >>= 1) {
                    float ov = __shfl_xor(bv, off);
                    int   ou = __shfl_xor(bu, off);
                    int   oj = __shfl_xor(bj, off);
                    if (ov < bv || (ov == bv && (ou > bu || (ou == bu && oj < bj))))
                        { bv = ov; bu = ou; bj = oj; }
                }
                j0 = bj;
                const float delta = bv;
                for (int j = lane; j <= n; j += 64) {
                    if (usedarr[j]) { uarr[parr[j]] += delta; varr[j] -= delta; }
                    else            { minvarr[j] -= delta; }
                }
                __syncthreads();
                if (parr[j0] == 0) break;
            }

            if (lane == 0) {
                int jj = j0, guard = 0;
                while (jj != 0 && guard++ <= n + 1) {
                    int j1 = wayarr[jj];
                    parr[jj] = parr[j1];
                    jj = j1;
                }
            }
            __syncthreads();
        }

        float contrib = 0.f;
        for (int j = lane; j <= n; j += 64) {
            if (j >= 1 && j <= m2) {
                int pi = parr[j];
                if (pi >= 1 && pi <= m1) {
                    float ix1 = fmaxf(r1x1[pi-1], r2x1[j-1]), iy1 = fmaxf(r1y1[pi-1], r2y1[j-1]);
                    float ix2 = fminf(r1x2[pi-1], r2x2[j-1]), iy2 = fminf(r1y2[pi-1], r2y2[j-1]);
                    float iw = fmaxf(ix2 - ix1, 0.f), ih = fmaxf(iy2 - iy1, 0.f);
                    float inter = iw * ih;
                    contrib += inter / (r1a[pi-1] + r2a[j-1] - inter);
                }
            }
        }
        #pragma unroll
        for (int off = 32; off; off >>= 1) contrib += __shfl_xor(contrib, off);
        if (lane == 0) sum_part[blk] = contrib;
    }
}

__global__ void det_finalize_kernel(const float* __restrict__ sum_part,
                                    const int* __restrict__ m1p,
                                    const int* __restrict__ m2p,
                                    float* __restrict__ out)
{
    if (threadIdx.x == 0 && blockIdx.x == 0) {
        float acc = 0.f;
        #pragma unroll
        for (int b = 0; b < BIMG; ++b) {
            int na = 0, nb = 0; float s = 0.f;
            #pragma unroll
            for (int c = 0; c < NCLS; ++c) {
                na += m1p[b * NCLS + c];
                nb += m2p[b * NCLS + c];
                s  += sum_part[b * NCLS + c];
            }
            float denom = fmaxf(fmaxf((float)na, (float)nb), 1.f);
            float per = 1.f - s / denom;
            bool bz = (na == 0) && (nb == 0);
            bool oz = ((na == 0) != (nb == 0));
            per = bz ? 0.f : (oz ? 1.f : per);
            acc += per;
        }
        out[0] = acc / (float)BIMG;
    }
}

extern "C" void kernel_launch(void* const* d_in, const int* in_sizes, int n_in,
                              void* d_out, int out_size, void* d_ws, size_t ws_size,
                              hipStream_t stream) {
    const float* b1 = (const float*)d_in[0];
    const float* b2 = (const float*)d_in[1];
    float* sum_part = (float*)d_ws;                     // [40] f32
    int*   m1_part  = (int*)(sum_part + BIMG * NCLS);   // [40] i32
    int*   m2_part  = m1_part + BIMG * NCLS;            // [40] i32

    det_match_kernel<<<BIMG * NCLS, 64, 0, stream>>>(b1, b2, sum_part, m1_part, m2_part);
    det_finalize_kernel<<<1, 64, 0, stream>>>(sum_part, m1_part, m2_part, (float*)d_out);
}